// Round 1
// 206.369 us; speedup vs baseline: 1.0206x; 1.0206x over previous
//
#include <hip/hip_runtime.h>

#define NROWS 524288
#define DDIM  64
#define HCENT 256
#define GRID  512
#define CPB   4   // 256-row chunks per block: 512*4*256 = 524288

typedef short bf16x8 __attribute__((ext_vector_type(8)));
typedef float f32x4  __attribute__((ext_vector_type(4)));

#define LOG2E 1.4426950408889634f
#define K2L   2.8853900817779268f   // 2*log2(e)
#define BIASF 80.0f

__device__ __forceinline__ float fast_exp2(float x) {
#if __has_builtin(__builtin_amdgcn_exp2f)
  return __builtin_amdgcn_exp2f(x);
#else
  return exp2f(x);
#endif
}

// fp32 -> bf16 with round-to-nearest-even, result in low 16 bits.
__device__ __forceinline__ unsigned bf16rne(unsigned u) {
  return (u + 0x7FFFu + ((u >> 16) & 1u)) >> 16;
}

// Precompute per-center constants into workspace, interleaved:
// cw[2h]   = -(c2[h]*log2e + BIAS)
// cw[2h+1] = w[h]
__global__ __launch_bounds__(256) void rbf_setup(const float* __restrict__ centers,
                                                 const float* __restrict__ w,
                                                 float* __restrict__ cw) {
  int h = threadIdx.x;
  const float* cp = centers + h * DDIM;
  float s = 0.f;
#pragma unroll
  for (int d = 0; d < DDIM; ++d) s = fmaf(cp[d], cp[d], s);
  cw[2 * h]     = -fmaf(s, LOG2E, BIASF);
  cw[2 * h + 1] = w[h];
}

__global__ __launch_bounds__(512, 4) void rbf_main(const float* __restrict__ X,
                                                   const float* __restrict__ bptr,
                                                   const float* __restrict__ centers,
                                                   const float* __restrict__ cw,
                                                   float* __restrict__ out) {
  // Centers as single RNE-rounded bf16 MFMA B-fragments, fragment-ordered for
  // conflict-free ds_read_b128: index = (ct*2+kc)*64 + lane, 16B per lane.
  // Precision note: outputs are ~1e-14 max (exp(-d2), d2 >~ 25); single bf16
  // product error ~5% relative => ~5e-16 absolute, far under the absmax
  // threshold (previous 3-product split measured 8.5e-22 — unused headroom).
  // LDS: 32KB + 2KB = 34KB -> occupancy is VGPR/wave-bound, not LDS-bound.
  __shared__ int4 BH[16 * 2 * 64];
  __shared__ float2 CWs[HCENT];   // (mc, w) per center

  const int tid  = threadIdx.x;
  const int wave = tid >> 6;      // 0..7
  const int lane = tid & 63;
  const int q    = lane >> 4;     // k-group / row-quad
  const int c    = lane & 15;     // col within tile (and A-row at load)

  // ---- stage centers (once per block; 8 waves x 4 (ct,kc) pairs) ----
#pragma unroll
  for (int i = 0; i < 4; ++i) {
    int pair = wave * 4 + i;      // 0..31
    int ct = pair >> 1;
    int kc = pair & 1;
    const float* src = centers + (ct * 16 + c) * DDIM + kc * 32 + q * 8;
    float4 f0 = reinterpret_cast<const float4*>(src)[0];
    float4 f1 = reinterpret_cast<const float4*>(src)[1];
    float xs[8] = {f0.x, f0.y, f0.z, f0.w, f1.x, f1.y, f1.z, f1.w};
    int hp[4];
#pragma unroll
    for (int p = 0; p < 4; ++p) {
      unsigned u0 = __float_as_uint(xs[2 * p]);
      unsigned u1 = __float_as_uint(xs[2 * p + 1]);
      hp[p] = (int)((bf16rne(u1) << 16) | bf16rne(u0));
    }
    BH[pair * 64 + lane] = make_int4(hp[0], hp[1], hp[2], hp[3]);
  }
  // stage cw: 512 threads -> 512 floats
  reinterpret_cast<float*>(CWs)[tid] = cw[tid];

  float bval = bptr[0];

  __syncthreads();  // LDS read-only hereafter; no barrier in the sweep loop

  const bf16x8* BHv = reinterpret_cast<const bf16x8*>(BH);

#pragma unroll 1
  for (int s = 0; s < CPB; ++s) {
    int rowbase = (blockIdx.x * CPB + s) * 256 + wave * 32;

    // ---- load X rows, RNE bf16 A-fragments, partial x2 in fp32 ----
    bf16x8 ah[2][2];
    float x2p[2];
#pragma unroll
    for (int rt = 0; rt < 2; ++rt) {
      const float* rp = X + (rowbase + rt * 16 + c) * DDIM + q * 8;
      float part = 0.f;
#pragma unroll
      for (int kc = 0; kc < 2; ++kc) {
        float4 f0 = reinterpret_cast<const float4*>(rp + kc * 32)[0];
        float4 f1 = reinterpret_cast<const float4*>(rp + kc * 32)[1];
        float xs[8] = {f0.x, f0.y, f0.z, f0.w, f1.x, f1.y, f1.z, f1.w};
        union { int i[4]; bf16x8 v; } uh;
#pragma unroll
        for (int p = 0; p < 4; ++p) {
          float x0 = xs[2 * p], x1 = xs[2 * p + 1];
          part = fmaf(x0, x0, part);
          part = fmaf(x1, x1, part);
          uh.i[p] = (int)((bf16rne(__float_as_uint(x1)) << 16) |
                          bf16rne(__float_as_uint(x0)));
        }
        ah[rt][kc] = uh.v;
      }
      x2p[rt] = part;   // k-partial; cross-k shfl deferred to epilogue
    }

    // ---- sweep 16 col-tiles: 2 MFMAs per (rt,ct) ----
    float psum[2][4] = {{0.f, 0.f, 0.f, 0.f}, {0.f, 0.f, 0.f, 0.f}};
#pragma unroll 2
    for (int ct = 0; ct < 16; ++ct) {
      int idx = ct * 128 + lane;
      bf16x8 bh0 = BHv[idx], bh1 = BHv[idx + 64];
      float2 mw = CWs[ct * 16 + c];   // (mc, w) via ds_read_b64, broadcast over q
#pragma unroll
      for (int rt = 0; rt < 2; ++rt) {
        f32x4 acc = {0.f, 0.f, 0.f, 0.f};
        acc = __builtin_amdgcn_mfma_f32_16x16x32_bf16(ah[rt][0], bh0, acc, 0, 0, 0);
        acc = __builtin_amdgcn_mfma_f32_16x16x32_bf16(ah[rt][1], bh1, acc, 0, 0, 0);
        // contribution = exp2(2L*a - (L*c2+B)) * w; row factor applied later
#pragma unroll
        for (int r = 0; r < 4; ++r) {
          float e = fast_exp2(fmaf(acc[r], K2L, mw.x));
          psum[rt][r] = fmaf(e, mw.y, psum[rt][r]);
        }
      }
    }

    // ---- reduce over the 16 col-lanes, apply row factor, store ----
#pragma unroll
    for (int rt = 0; rt < 2; ++rt) {
      // complete x2 across k-groups now (off the sweep's critical path)
      float part = x2p[rt];
      part += __shfl_xor(part, 16, 64);
      part += __shfl_xor(part, 32, 64);
#pragma unroll
      for (int r = 0; r < 4; ++r) {
        float v = psum[rt][r];
        v += __shfl_xor(v, 1, 64);
        v += __shfl_xor(v, 2, 64);
        v += __shfl_xor(v, 4, 64);
        v += __shfl_xor(v, 8, 64);
        // x2 of row q*4+r lives in lanes with c == q*4+r (replicated over q)
        float x2row = __shfl(part, q * 4 + r, 64);
        float rowf = fast_exp2(fmaf(-LOG2E, x2row, BIASF));
        psum[rt][r] = fmaf(v, rowf, bval);
      }
      if (c == 0) {
        float4 o = make_float4(psum[rt][0], psum[rt][1], psum[rt][2], psum[rt][3]);
        *reinterpret_cast<float4*>(out + rowbase + rt * 16 + q * 4) = o;
      }
    }
  }
}

extern "C" void kernel_launch(void* const* d_in, const int* in_sizes, int n_in,
                              void* d_out, int out_size, void* d_ws, size_t ws_size,
                              hipStream_t stream) {
  const float* X       = (const float*)d_in[0];
  const float* centers = (const float*)d_in[1];
  const float* w       = (const float*)d_in[2];
  const float* b       = (const float*)d_in[3];
  float* out = (float*)d_out;
  float* cw  = (float*)d_ws;   // 512 floats, interleaved (mc, w)

  rbf_setup<<<1, 256, 0, stream>>>(centers, w, cw);
  rbf_main<<<GRID, 512, 0, stream>>>(X, b, centers, cw, out);
}

// Round 3
// 206.368 us; speedup vs baseline: 1.0206x; 1.0000x over previous
//
#include <hip/hip_runtime.h>

#define NROWS 524288
#define DDIM  64
#define HCENT 256
#define GRID  512
#define CPB   4   // 256-row chunks per block: 512*4*256 = 524288

typedef short bf16x8 __attribute__((ext_vector_type(8)));
typedef float f32x4  __attribute__((ext_vector_type(4)));

#define LOG2E 1.4426950408889634f
#define K2L   2.8853900817779268f   // 2*log2(e)
#define BIASF 80.0f

__device__ __forceinline__ float fast_exp2(float x) {
#if __has_builtin(__builtin_amdgcn_exp2f)
  return __builtin_amdgcn_exp2f(x);
#else
  return exp2f(x);
#endif
}

// Single fused kernel (no setup launch, no workspace).
// NUMERICS = round-0 proven scheme (absmax 8.5e-22, 11x threshold margin):
//   - centers/X split to bf16 hi (truncate) + lo (residual, truncate)
//   - 3 products per k-chunk: ah*bh + al*bh + ah*bl  (al*bl second-order)
//   - exponent = fmaf(acc, 2*log2e, -(L*c2+BIAS)) in fp32
// Threshold is ~3.1% of max|ref| (floor_eps_k=8 * bf16 eps); single-product
// bf16 measured 6.8e-21..1.7e-20 across rounds == structurally marginal. Do
// NOT drop the split or pre-scale centers before rounding (round-2 fail).
// STRUCTURE = round-2 fusion: every block stages all 256 centers anyway, so
// c2[h] is computed in-block during staging (fp32 tree-sum, ~1e-23 abs
// contribution) and the old 1-block rbf_setup launch + d_ws are eliminated.
// LDS: 32KB(BH) + 32KB(BL) + 2KB = 66KB -> 2 blocks/CU, 16 waves/CU.
__global__ __launch_bounds__(512, 4) void rbf_main(const float* __restrict__ X,
                                                   const float* __restrict__ bptr,
                                                   const float* __restrict__ centers,
                                                   const float* __restrict__ w,
                                                   float* __restrict__ out) {
  // Fragment-ordered for conflict-free ds_read_b128: index = (ct*2+kc)*64+lane
  __shared__ int4 BH[16 * 2 * 64];
  __shared__ int4 BL[16 * 2 * 64];
  __shared__ float2 CWs[HCENT];   // (mc, w) per center; mc = -(L*c2 + BIAS)

  const int tid  = threadIdx.x;
  const int wave = tid >> 6;      // 0..7
  const int lane = tid & 63;
  const int q    = lane >> 4;     // k-group / row-quad
  const int c    = lane & 15;     // col within tile (and A-row at load)

  // ---- stage centers (hi+lo) + compute c2 (8 waves x 4 (ct,kc) pairs) ----
  float c2acc[2] = {0.f, 0.f};
#pragma unroll
  for (int i = 0; i < 4; ++i) {
    int pair = wave * 4 + i;      // 0..31
    int ct = pair >> 1;
    int kc = pair & 1;
    const float* src = centers + (ct * 16 + c) * DDIM + kc * 32 + q * 8;
    float4 f0 = reinterpret_cast<const float4*>(src)[0];
    float4 f1 = reinterpret_cast<const float4*>(src)[1];
    float xs[8] = {f0.x, f0.y, f0.z, f0.w, f1.x, f1.y, f1.z, f1.w};
    int hp[4], lp[4];
    float part = 0.f;
#pragma unroll
    for (int p = 0; p < 4; ++p) {
      float x0 = xs[2 * p], x1 = xs[2 * p + 1];
      part = fmaf(x0, x0, part);
      part = fmaf(x1, x1, part);
      unsigned u0 = __float_as_uint(x0);
      unsigned u1 = __float_as_uint(x1);
      float l0 = x0 - __uint_as_float(u0 & 0xFFFF0000u);
      float l1 = x1 - __uint_as_float(u1 & 0xFFFF0000u);
      hp[p] = (int)((u1 & 0xFFFF0000u) | (u0 >> 16));
      lp[p] = (int)((__float_as_uint(l1) & 0xFFFF0000u) | (__float_as_uint(l0) >> 16));
    }
    // c2 partial for center ct*16+c: this kc-half summed across q-groups
    part += __shfl_xor(part, 16, 64);
    part += __shfl_xor(part, 32, 64);
    c2acc[i >> 1] += part;        // i=0,1 -> local ct 0 (kc 0,1); i=2,3 -> 1
    int idx = pair * 64 + lane;
    BH[idx] = make_int4(hp[0], hp[1], hp[2], hp[3]);
    BL[idx] = make_int4(lp[0], lp[1], lp[2], lp[3]);
  }
  if (lane < 16) {
#pragma unroll
    for (int t = 0; t < 2; ++t) {
      int h = (wave * 2 + t) * 16 + lane;
      CWs[h] = make_float2(-fmaf(c2acc[t], LOG2E, BIASF), w[h]);
    }
  }

  float bval = bptr[0];

  __syncthreads();  // LDS read-only hereafter; no barrier in the sweep loop

  const bf16x8* BHv = reinterpret_cast<const bf16x8*>(BH);
  const bf16x8* BLv = reinterpret_cast<const bf16x8*>(BL);

#pragma unroll 1
  for (int s = 0; s < CPB; ++s) {
    int rowbase = (blockIdx.x * CPB + s) * 256 + wave * 32;

    // ---- load X rows, split to bf16 hi/lo A-fragments, partial x2 ----
    bf16x8 ah[2][2], al[2][2];
    float x2p[2];
#pragma unroll
    for (int rt = 0; rt < 2; ++rt) {
      const float* rp = X + (rowbase + rt * 16 + c) * DDIM + q * 8;
      float part = 0.f;
#pragma unroll
      for (int kc = 0; kc < 2; ++kc) {
        float4 f0 = reinterpret_cast<const float4*>(rp + kc * 32)[0];
        float4 f1 = reinterpret_cast<const float4*>(rp + kc * 32)[1];
        float xs[8] = {f0.x, f0.y, f0.z, f0.w, f1.x, f1.y, f1.z, f1.w};
        union { int i[4]; bf16x8 v; } uh, ul;
#pragma unroll
        for (int p = 0; p < 4; ++p) {
          float x0 = xs[2 * p], x1 = xs[2 * p + 1];
          part = fmaf(x0, x0, part);
          part = fmaf(x1, x1, part);
          unsigned u0 = __float_as_uint(x0);
          unsigned u1 = __float_as_uint(x1);
          float l0 = x0 - __uint_as_float(u0 & 0xFFFF0000u);
          float l1 = x1 - __uint_as_float(u1 & 0xFFFF0000u);
          uh.i[p] = (int)((u1 & 0xFFFF0000u) | (u0 >> 16));
          ul.i[p] = (int)((__float_as_uint(l1) & 0xFFFF0000u) | (__float_as_uint(l0) >> 16));
        }
        ah[rt][kc] = uh.v;
        al[rt][kc] = ul.v;
      }
      x2p[rt] = part;   // k-partial; cross-k shfl deferred to epilogue
    }

    // ---- sweep 16 col-tiles: 6 MFMAs per (rt,ct) (3-product split) ----
    float psum[2][4] = {{0.f, 0.f, 0.f, 0.f}, {0.f, 0.f, 0.f, 0.f}};
#pragma unroll 2
    for (int ct = 0; ct < 16; ++ct) {
      int idx = ct * 128 + lane;
      bf16x8 bh0 = BHv[idx], bh1 = BHv[idx + 64];
      bf16x8 bl0 = BLv[idx], bl1 = BLv[idx + 64];
      float2 mw = CWs[ct * 16 + c];   // (mc, w); broadcast over q -> no conflict
#pragma unroll
      for (int rt = 0; rt < 2; ++rt) {
        f32x4 acc = {0.f, 0.f, 0.f, 0.f};
        acc = __builtin_amdgcn_mfma_f32_16x16x32_bf16(ah[rt][0], bh0, acc, 0, 0, 0);
        acc = __builtin_amdgcn_mfma_f32_16x16x32_bf16(ah[rt][1], bh1, acc, 0, 0, 0);
        acc = __builtin_amdgcn_mfma_f32_16x16x32_bf16(al[rt][0], bh0, acc, 0, 0, 0);
        acc = __builtin_amdgcn_mfma_f32_16x16x32_bf16(al[rt][1], bh1, acc, 0, 0, 0);
        acc = __builtin_amdgcn_mfma_f32_16x16x32_bf16(ah[rt][0], bl0, acc, 0, 0, 0);
        acc = __builtin_amdgcn_mfma_f32_16x16x32_bf16(ah[rt][1], bl1, acc, 0, 0, 0);
        // contribution = exp2(2L*a - (L*c2+B)) * w; row factor applied later
#pragma unroll
        for (int r = 0; r < 4; ++r) {
          float e = fast_exp2(fmaf(acc[r], K2L, mw.x));
          psum[rt][r] = fmaf(e, mw.y, psum[rt][r]);
        }
      }
    }

    // ---- reduce over the 16 col-lanes, apply row factor, store ----
#pragma unroll
    for (int rt = 0; rt < 2; ++rt) {
      // complete x2 across k-groups now (off the sweep's critical path)
      float part = x2p[rt];
      part += __shfl_xor(part, 16, 64);
      part += __shfl_xor(part, 32, 64);
#pragma unroll
      for (int r = 0; r < 4; ++r) {
        float v = psum[rt][r];
        v += __shfl_xor(v, 1, 64);
        v += __shfl_xor(v, 2, 64);
        v += __shfl_xor(v, 4, 64);
        v += __shfl_xor(v, 8, 64);
        // x2 of row q*4+r lives in lanes with c == q*4+r (replicated over q)
        float x2row = __shfl(part, q * 4 + r, 64);
        float rowf = fast_exp2(fmaf(-LOG2E, x2row, BIASF));
        psum[rt][r] = fmaf(v, rowf, bval);
      }
      if (c == 0) {
        float4 o = make_float4(psum[rt][0], psum[rt][1], psum[rt][2], psum[rt][3]);
        *reinterpret_cast<float4*>(out + rowbase + rt * 16 + q * 4) = o;
      }
    }
  }
}

extern "C" void kernel_launch(void* const* d_in, const int* in_sizes, int n_in,
                              void* d_out, int out_size, void* d_ws, size_t ws_size,
                              hipStream_t stream) {
  const float* X       = (const float*)d_in[0];
  const float* centers = (const float*)d_in[1];
  const float* w       = (const float*)d_in[2];
  const float* b       = (const float*)d_in[3];
  float* out = (float*)d_out;
  (void)d_ws; (void)ws_size;   // workspace unused: setup fused into rbf_main

  rbf_main<<<GRID, 512, 0, stream>>>(X, b, centers, w, out);
}

// Round 4
// 205.013 us; speedup vs baseline: 1.0273x; 1.0066x over previous
//
#include <hip/hip_runtime.h>

#define NROWS 524288
#define DDIM  64
#define HCENT 256
#define GRID  512
#define CPB   4   // 256-row chunks per block: 512*4*256 = 524288

typedef _Float16 half8 __attribute__((ext_vector_type(8)));
typedef float    f32x4 __attribute__((ext_vector_type(4)));

#define LOG2E 1.4426950408889634f
#define K2L   2.8853900817779268f   // 2*log2(e)
#define BIASF 80.0f

__device__ __forceinline__ float fast_exp2(float x) {
#if __has_builtin(__builtin_amdgcn_exp2f)
  return __builtin_amdgcn_exp2f(x);
#else
  return exp2f(x);
#endif
}

// Single fused kernel (no setup launch, no workspace).
// NUMERICS: single fp16 product. Threshold is ~3.1% of max|ref|
// (floor_eps_k=8 * bf16 eps ~ 9.6e-21). Evidence chain:
//   - single bf16-RNE product measured absmax 6.78e-21 (1.4x margin, marginal)
//   - fp16 RNE eps is 8x smaller (2^-12 vs 2^-9); cross-term rounding error is
//     first-order in eps => expected ~8.5e-22, same as the round-0 hi/lo split
//     (measured 8.47e-22) at 1/3 the MFMA count and 1/2 the LDS.
//   - x2, c2, exponent all fp32; centers NOT pre-scaled (round-2 fail lesson).
// STRUCTURE: c2 computed in-block during center staging (fp32 tree-sum,
// bit-identical result to the old setup kernel per round 3). X is
// double-buffered in registers across chunks (rawA/rawB, statically indexed)
// so chunk s+1's global loads are in flight during chunk s's sweep -> HBM
// latency hides under compute instead of stalling each wave per chunk.
// LDS: 32KB(BH) + 2KB(CWs). Occupancy: VGPR-capped 2 blocks/CU (16 waves/CU).
__global__ __launch_bounds__(512, 4) void rbf_main(const float* __restrict__ X,
                                                   const float* __restrict__ bptr,
                                                   const float* __restrict__ centers,
                                                   const float* __restrict__ w,
                                                   float* __restrict__ out);

__device__ __forceinline__ void load_chunk(const float* __restrict__ X, int rowbase,
                                           int c, int q, float4 (&raw)[8]) {
#pragma unroll
  for (int rt = 0; rt < 2; ++rt) {
    const float* rp = X + (rowbase + rt * 16 + c) * DDIM + q * 8;
#pragma unroll
    for (int kc = 0; kc < 2; ++kc) {
      raw[rt * 4 + kc * 2 + 0] = reinterpret_cast<const float4*>(rp + kc * 32)[0];
      raw[rt * 4 + kc * 2 + 1] = reinterpret_cast<const float4*>(rp + kc * 32)[1];
    }
  }
}

__device__ __forceinline__ void convert_chunk(const float4 (&raw)[8],
                                              half8 (&a)[2][2], float (&x2p)[2]) {
#pragma unroll
  for (int rt = 0; rt < 2; ++rt) {
    float part = 0.f;
#pragma unroll
    for (int kc = 0; kc < 2; ++kc) {
      const float4 f0 = raw[rt * 4 + kc * 2 + 0];
      const float4 f1 = raw[rt * 4 + kc * 2 + 1];
      const float xs[8] = {f0.x, f0.y, f0.z, f0.w, f1.x, f1.y, f1.z, f1.w};
      union { _Float16 h[8]; half8 v; } u;
#pragma unroll
      for (int p = 0; p < 8; ++p) {
        part = fmaf(xs[p], xs[p], part);
        u.h[p] = (_Float16)xs[p];   // v_cvt_f16_f32, RNE
      }
      a[rt][kc] = u.v;
    }
    x2p[rt] = part;   // k-partial; cross-k shfl deferred to epilogue
  }
}

__device__ __forceinline__ void chunk_body(const float* __restrict__ X, int rowbase,
                                           bool prefetch,
                                           const float4 (&cur)[8], float4 (&nxt)[8],
                                           const half8* __restrict__ BHv,
                                           const float2* __restrict__ CWs,
                                           int lane, int q, int c, float bval,
                                           float* __restrict__ out) {
  // issue next chunk's loads first so they fly during this chunk's sweep
  if (prefetch) load_chunk(X, rowbase + 256, c, q, nxt);

  half8 a[2][2];
  float x2p[2];
  convert_chunk(cur, a, x2p);

  // ---- sweep 16 col-tiles: 2 fp16 MFMAs per (rt,ct) ----
  float psum[2][4] = {{0.f, 0.f, 0.f, 0.f}, {0.f, 0.f, 0.f, 0.f}};
#pragma unroll 2
  for (int ct = 0; ct < 16; ++ct) {
    int idx = ct * 128 + lane;
    half8 bh0 = BHv[idx], bh1 = BHv[idx + 64];
    float2 mw = CWs[ct * 16 + c];   // (mc, w); broadcast over q -> no conflict
#pragma unroll
    for (int rt = 0; rt < 2; ++rt) {
      f32x4 acc = {0.f, 0.f, 0.f, 0.f};
      acc = __builtin_amdgcn_mfma_f32_16x16x32_f16(a[rt][0], bh0, acc, 0, 0, 0);
      acc = __builtin_amdgcn_mfma_f32_16x16x32_f16(a[rt][1], bh1, acc, 0, 0, 0);
      // contribution = exp2(2L*xc - (L*c2+B)) * w; row factor applied later
#pragma unroll
      for (int r = 0; r < 4; ++r) {
        float e = fast_exp2(fmaf(acc[r], K2L, mw.x));
        psum[rt][r] = fmaf(e, mw.y, psum[rt][r]);
      }
    }
  }

  // ---- reduce over the 16 col-lanes, apply row factor, store ----
#pragma unroll
  for (int rt = 0; rt < 2; ++rt) {
    // complete x2 across k-groups now (off the sweep's critical path)
    float part = x2p[rt];
    part += __shfl_xor(part, 16, 64);
    part += __shfl_xor(part, 32, 64);
#pragma unroll
    for (int r = 0; r < 4; ++r) {
      float v = psum[rt][r];
      v += __shfl_xor(v, 1, 64);
      v += __shfl_xor(v, 2, 64);
      v += __shfl_xor(v, 4, 64);
      v += __shfl_xor(v, 8, 64);
      // x2 of row q*4+r lives in lanes with c == q*4+r (replicated over q)
      float x2row = __shfl(part, q * 4 + r, 64);
      float rowf = fast_exp2(fmaf(-LOG2E, x2row, BIASF));
      psum[rt][r] = fmaf(v, rowf, bval);
    }
    if (c == 0) {
      float4 o = make_float4(psum[rt][0], psum[rt][1], psum[rt][2], psum[rt][3]);
      *reinterpret_cast<float4*>(out + rowbase + rt * 16 + q * 4) = o;
    }
  }
}

__global__ __launch_bounds__(512, 4) void rbf_main(const float* __restrict__ X,
                                                   const float* __restrict__ bptr,
                                                   const float* __restrict__ centers,
                                                   const float* __restrict__ w,
                                                   float* __restrict__ out) {
  // Fragment-ordered for conflict-free ds_read_b128: index = (ct*2+kc)*64+lane
  __shared__ int4 BH[16 * 2 * 64];
  __shared__ float2 CWs[HCENT];   // (mc, w) per center; mc = -(L*c2 + BIAS)

  const int tid  = threadIdx.x;
  const int wave = tid >> 6;      // 0..7
  const int lane = tid & 63;
  const int q    = lane >> 4;     // k-group / row-quad
  const int c    = lane & 15;     // col within tile (and A-row at load)

  // ---- stage centers (fp16) + compute c2 (8 waves x 4 (ct,kc) pairs) ----
  float c2acc[2] = {0.f, 0.f};
#pragma unroll
  for (int i = 0; i < 4; ++i) {
    int pair = wave * 4 + i;      // 0..31
    int ct = pair >> 1;
    int kc = pair & 1;
    const float* src = centers + (ct * 16 + c) * DDIM + kc * 32 + q * 8;
    float4 f0 = reinterpret_cast<const float4*>(src)[0];
    float4 f1 = reinterpret_cast<const float4*>(src)[1];
    const float xs[8] = {f0.x, f0.y, f0.z, f0.w, f1.x, f1.y, f1.z, f1.w};
    union { _Float16 h[8]; int4 i4; } u;
    float part = 0.f;
#pragma unroll
    for (int p = 0; p < 8; ++p) {
      part = fmaf(xs[p], xs[p], part);
      u.h[p] = (_Float16)xs[p];
    }
    // c2 partial for center ct*16+c: this kc-half summed across q-groups
    part += __shfl_xor(part, 16, 64);
    part += __shfl_xor(part, 32, 64);
    c2acc[i >> 1] += part;        // i=0,1 -> local ct 0 (kc 0,1); i=2,3 -> 1
    BH[pair * 64 + lane] = u.i4;
  }
  if (lane < 16) {
#pragma unroll
    for (int t = 0; t < 2; ++t) {
      int h = (wave * 2 + t) * 16 + lane;
      CWs[h] = make_float2(-fmaf(c2acc[t], LOG2E, BIASF), w[h]);
    }
  }

  float bval = bptr[0];

  __syncthreads();  // LDS read-only hereafter; no barrier in the sweep loop

  const half8* BHv = reinterpret_cast<const half8*>(BH);

  const int rb0 = blockIdx.x * CPB * 256 + wave * 32;

  float4 rawA[8], rawB[8];
  load_chunk(X, rb0, c, q, rawA);

  // fully unrolled, statically-indexed double buffer (rule: no runtime bank idx)
  chunk_body(X, rb0 + 0 * 256, true,  rawA, rawB, BHv, CWs, lane, q, c, bval, out);
  chunk_body(X, rb0 + 1 * 256, true,  rawB, rawA, BHv, CWs, lane, q, c, bval, out);
  chunk_body(X, rb0 + 2 * 256, true,  rawA, rawB, BHv, CWs, lane, q, c, bval, out);
  chunk_body(X, rb0 + 3 * 256, false, rawB, rawA, BHv, CWs, lane, q, c, bval, out);
}

extern "C" void kernel_launch(void* const* d_in, const int* in_sizes, int n_in,
                              void* d_out, int out_size, void* d_ws, size_t ws_size,
                              hipStream_t stream) {
  const float* X       = (const float*)d_in[0];
  const float* centers = (const float*)d_in[1];
  const float* w       = (const float*)d_in[2];
  const float* b       = (const float*)d_in[3];
  float* out = (float*)d_out;
  (void)d_ws; (void)ws_size;   // workspace unused: setup fused into rbf_main

  rbf_main<<<GRID, 512, 0, stream>>>(X, b, centers, w, out);
}